// Round 10
// baseline (838.414 us; speedup 1.0000x reference)
//
#include <hip/hip_runtime.h>

// ClassicalSelfAttention: out = softmax((X R)(X E)^T / 32) @ X,  X[8192][1024] fp32.
//  - logits = X (R E^T) X^T / 32. Precompute Mt = E R^T, Y = X Mt^T, L = Y X^T / 32.
//  - Precision-critical GEMMs via f16 hi/lo split (3 MFMA products) -> ~fp32 accuracy.
//  - pexp: per-row softmax of L -> f16 P written IN-PLACE over L (row stride 16384 f16).
//  - gemm_pv: plain f16 GEMM out = P @ Xt^T, 64x128 tile, BK=64, dbuf, 2 blocks/CU.
// R2: conflict-free swizzle ((row>>1)&3)<<4. XCD chunking regressed (identity optimal).
// R3: 128^2 1-phase caps at 43%.
// R4: 256^2 8-wave dbuf, 1 barrier/K-step -> 58.6% / 873 TF.
// R5 LESSON: launch_bounds min-waves beyond register budget -> full acc spill (22x).
// R6 LESSON: 8-phase with LOPSIDED phases + staging issued in last phase regressed.
// R7 BUG: pv K-loop trip count halved. R8: fixed; but Y-on-big-kernel (128-block grid,
//   half GPU idle) and pv 1-wave/SIMD net-regressed vs R4. Grid >= 2x CUs first.
// R9: Y back to gemm_abt_s (512 blocks). pv 64x128 dbuf (48KB -> 2 blk/CU). L-GEMM
//   balanced 8-phase: phase = C-quadrant (uniform 12 ds_read + 24 MFMA), all 8 staging
//   loads issued in phases 0-1 so boundary vmcnt(0) is ~free.

typedef _Float16 f16;
typedef _Float16 f16x4 __attribute__((ext_vector_type(4)));
typedef _Float16 f16x8 __attribute__((ext_vector_type(8)));
typedef float    f32x4 __attribute__((ext_vector_type(4)));
typedef unsigned int u32;

#define N_ROWS 8192
#define D_DIM  1024
#define LOG2E  1.44269504088896340736f

__device__ __forceinline__ void gload_lds16(const void* g, void* l) {
  __builtin_amdgcn_global_load_lds(
      (const __attribute__((address_space(1))) u32*)g,
      (__attribute__((address_space(3))) u32*)l, 16, 0, 0);
}

// ---- BK=32 tiles (64 B rows), swizzle byte^=(((row>>1)&3)<<4) ----
__device__ __forceinline__ f16x8 read_frag(const f16* tile, int row, int lane) {
  int kb = ((lane >> 4) & 3) << 4;
  int phys = row * 64 + (kb ^ (((row >> 1) & 3) << 4));
  return *(const f16x8*)((const char*)tile + phys);
}

// ---- BK=64 tiles (128 B rows), swizzle byte^=((row&7)<<4) ----
__device__ __forceinline__ f16x8 read_frag64(const f16* tile, int row, int lane, int ks2) {
  int kb = ks2 * 64 + (((lane >> 4) & 3) << 4);
  int phys = row * 128 + (kb ^ ((row & 7) << 4));
  return *(const f16x8*)((const char*)tile + phys);
}

// fp32 -> f16 hi/lo split, vectorized x4
__global__ __launch_bounds__(256) void splitk(const float* __restrict__ in,
                                              f16* __restrict__ hi, f16* __restrict__ lo,
                                              int n4) {
  int i = blockIdx.x * 256 + threadIdx.x;
  if (i >= n4) return;
  float4 v = ((const float4*)in)[i];
  float vv[4] = {v.x, v.y, v.z, v.w};
  f16x4 h, l;
#pragma unroll
  for (int j = 0; j < 4; ++j) {
    f16 hh = (f16)vv[j];
    h[j] = hh;
    l[j] = (f16)(vv[j] - (float)hh);
  }
  *(f16x4*)(hi + (size_t)i * 4) = h;
  *(f16x4*)(lo + (size_t)i * 4) = l;
}

// X[8192][1024] fp32 -> Xt[1024][8192] f16
__global__ __launch_bounds__(256) void transpose_cast(const float* __restrict__ X,
                                                      f16* __restrict__ Xt) {
  __shared__ float tile[32][33];
  int bx = blockIdx.x, by = blockIdx.y;
  int tx = threadIdx.x & 31, ty0 = threadIdx.x >> 5;
#pragma unroll
  for (int r = 0; r < 4; ++r) {
    int ty = ty0 + r * 8;
    tile[ty][tx] = X[(size_t)(by * 32 + ty) * D_DIM + bx * 32 + tx];
  }
  __syncthreads();
#pragma unroll
  for (int r = 0; r < 4; ++r) {
    int ty = ty0 + r * 8;
    Xt[(size_t)(bx * 32 + ty) * N_ROWS + by * 32 + tx] = (f16)tile[tx][ty];
  }
}

// Small split-3 GEMM for Mt (64 blocks) and Y (512 blocks). Tile 128x128, BK=32.
__global__ __launch_bounds__(256) void gemm_abt_s(
    const f16* __restrict__ Ahi, const f16* __restrict__ Alo,
    const f16* __restrict__ Bhi, const f16* __restrict__ Blo,
    int Ncols, f16* __restrict__ Chi, f16* __restrict__ Clo) {
  __shared__ __align__(16) f16 lds[4 * 4096];  // Ahi | Alo | Bhi | Blo, each [128][32]
  const int t = threadIdx.x, w = t >> 6, l = t & 63;
  const int bn = blockIdx.x, bm = blockIdx.y;
  const int wr = (w >> 1) * 64, wc = (w & 1) * 64;
  const char* srcs[4];
  srcs[0] = (const char*)(Ahi + (size_t)bm * 128 * 1024);
  srcs[1] = (const char*)(Alo + (size_t)bm * 128 * 1024);
  srcs[2] = (const char*)(Bhi + (size_t)bn * 128 * 1024);
  srcs[3] = (const char*)(Blo + (size_t)bn * 128 * 1024);
  f32x4 acc[4][4] = {};
  for (int ks = 0; ks < 32; ++ks) {
#pragma unroll
    for (int tt = 0; tt < 4; ++tt)
#pragma unroll
      for (int j = 0; j < 2; ++j) {
        int seg = j * 4 + w;
        int p = seg * 1024 + l * 16;
        int r = p >> 6;
        int sw = (p & 63) ^ (((r >> 1) & 3) << 4);
        gload_lds16(srcs[tt] + (size_t)r * 2048 + ks * 64 + sw,
                    (char*)lds + tt * 8192 + seg * 1024);
      }
    __syncthreads();
    f16x8 ah[4], al[4], bh[4], bl[4];
#pragma unroll
    for (int m = 0; m < 4; ++m) {
      int row = wr + m * 16 + (l & 15);
      ah[m] = read_frag(lds, row, l);
      al[m] = read_frag(lds + 4096, row, l);
    }
#pragma unroll
    for (int n = 0; n < 4; ++n) {
      int row = wc + n * 16 + (l & 15);
      bh[n] = read_frag(lds + 8192, row, l);
      bl[n] = read_frag(lds + 12288, row, l);
    }
#pragma unroll
    for (int m = 0; m < 4; ++m)
#pragma unroll
      for (int n = 0; n < 4; ++n) {
        acc[m][n] = __builtin_amdgcn_mfma_f32_16x16x32_f16(ah[m], bh[n], acc[m][n], 0, 0, 0);
        acc[m][n] = __builtin_amdgcn_mfma_f32_16x16x32_f16(ah[m], bl[n], acc[m][n], 0, 0, 0);
        acc[m][n] = __builtin_amdgcn_mfma_f32_16x16x32_f16(al[m], bh[n], acc[m][n], 0, 0, 0);
      }
    __syncthreads();
  }
#pragma unroll
  for (int m = 0; m < 4; ++m)
#pragma unroll
    for (int n = 0; n < 4; ++n)
#pragma unroll
      for (int j = 0; j < 4; ++j) {
        int row = bm * 128 + wr + m * 16 + ((l >> 4) << 2) + j;
        int col = bn * 128 + wc + n * 16 + (l & 15);
        float v = acc[m][n][j];
        size_t idx = (size_t)row * Ncols + col;
        f16 hh = (f16)v;
        Chi[idx] = hh;
        Clo[idx] = (f16)(v - (float)hh);
      }
}

// Big split-3 GEMM for L = Y X^T / 32. Tile 256x256, BK=32, 512 threads (8 waves 2Mx4N).
// LDS dbuf 2x64 KB. Balanced 8-phase-style: per K-tile, 4 uniform phases; phase =
// C-quadrant (mh,nh): 12 ds_read_b128 + 24 MFMA each (B re-read per m-half for
// uniformity). All 8 staging loads for kt+1 issued in phases 0-1; the boundary
// vmcnt(0) in phase 3 fires ~2 phases after last issue -> near-free.
__global__ __launch_bounds__(512, 2) void gemm_abt_big(
    const f16* __restrict__ Ahi, const f16* __restrict__ Alo,
    const f16* __restrict__ Bhi, const f16* __restrict__ Blo,
    float scale, float* __restrict__ C) {
  __shared__ __align__(16) f16 lds[2][4 * 8192];  // per buf: Ahi|Alo|Bhi|Blo [256][32]
  const int t = threadIdx.x, w = t >> 6, l = t & 63;
  const int bn = blockIdx.x, bm = blockIdx.y;
  const int wm = w >> 2, wn = w & 3;
  const char* srcs[4];
  srcs[0] = (const char*)(Ahi + (size_t)bm * 256 * 1024);
  srcs[1] = (const char*)(Alo + (size_t)bm * 256 * 1024);
  srcs[2] = (const char*)(Bhi + (size_t)bn * 256 * 1024);
  srcs[3] = (const char*)(Blo + (size_t)bn * 256 * 1024);

  // Stage rounds [h*4, h*4+4) of K-tile kt into lds[buf]. h=0: Ahi+Alo, h=1: Bhi+Blo.
#define STAGE_HALF(buf, kt, h)                                               \
  {                                                                          \
    _Pragma("unroll") for (int rnd = (h) * 4; rnd < (h) * 4 + 4; ++rnd) {    \
      int phys = rnd * 8192 + t * 16;                                        \
      int tile = phys >> 14;                                                 \
      int r = (phys & 16383) >> 6;                                           \
      int q = phys & 63;                                                     \
      int sw = q ^ (((r >> 1) & 3) << 4);                                    \
      gload_lds16(srcs[tile] + (size_t)r * 2048 + (kt)*64 + sw,              \
                  (char*)&lds[buf][0] + phys);                               \
    }                                                                        \
  }

  f32x4 acc[8][4] = {};
  STAGE_HALF(0, 0, 0);
  STAGE_HALF(0, 0, 1);
  __syncthreads();  // prologue: full drain
  int cur = 0;
  for (int kt = 0; kt < 32; ++kt) {
    const f16* Lb = &lds[cur][0];
    const int nxt = cur ^ 1;
#pragma unroll
    for (int ph = 0; ph < 4; ++ph) {
      const int mh = ph >> 1, nh = ph & 1;
      f16x8 ah[4], al[4], bh2[2], bl2[2];
#pragma unroll
      for (int i = 0; i < 4; ++i) {
        int row = wm * 128 + (mh * 4 + i) * 16 + (l & 15);
        ah[i] = read_frag(Lb, row, l);
        al[i] = read_frag(Lb + 8192, row, l);
      }
#pragma unroll
      for (int j = 0; j < 2; ++j) {
        int row = wn * 64 + (nh * 2 + j) * 16 + (l & 15);
        bh2[j] = read_frag(Lb + 16384, row, l);
        bl2[j] = read_frag(Lb + 24576, row, l);
      }
      if (kt < 31 && ph < 2) STAGE_HALF(nxt, kt + 1, ph);  // all 8 issued by end of ph1
      __builtin_amdgcn_s_barrier();
      asm volatile("s_waitcnt lgkmcnt(0)" ::: "memory");
      __builtin_amdgcn_sched_barrier(0);  // rule 18: keep MFMAs below the wait
      __builtin_amdgcn_s_setprio(1);
#pragma unroll
      for (int i = 0; i < 4; ++i)
#pragma unroll
        for (int j = 0; j < 2; ++j) {
          const int m = mh * 4 + i, n = nh * 2 + j;
          acc[m][n] = __builtin_amdgcn_mfma_f32_16x16x32_f16(ah[i], bh2[j], acc[m][n], 0, 0, 0);
          acc[m][n] = __builtin_amdgcn_mfma_f32_16x16x32_f16(ah[i], bl2[j], acc[m][n], 0, 0, 0);
          acc[m][n] = __builtin_amdgcn_mfma_f32_16x16x32_f16(al[i], bh2[j], acc[m][n], 0, 0, 0);
        }
      __builtin_amdgcn_s_setprio(0);
      __builtin_amdgcn_sched_barrier(0);
      if (ph == 3) {
        // Boundary: only vmcnt wait per K-tile; last staging load issued 2 phases ago.
        asm volatile("s_waitcnt vmcnt(0)" ::: "memory");
      }
      __builtin_amdgcn_s_barrier();
    }
    cur ^= 1;
  }
#undef STAGE_HALF
#pragma unroll
  for (int m = 0; m < 8; ++m)
#pragma unroll
    for (int n = 0; n < 4; ++n)
#pragma unroll
      for (int j = 0; j < 4; ++j) {
        int row = bm * 256 + wm * 128 + m * 16 + ((l >> 4) << 2) + j;
        int col = bn * 256 + wn * 64 + n * 16 + (l & 15);
        C[(size_t)row * N_ROWS + col] = acc[m][n][j] * scale;
      }
}

// Row softmax: read L row (8192 f32) into registers, reduce max & sum(exp),
// write P = exp(L-m)/S as f16 IN-PLACE over the first half of the row.
// P row stride = 16384 f16 elements (= 32 KB = one L row).
__global__ __launch_bounds__(256) void pexp(const float* __restrict__ L,
                                            f16* __restrict__ P) {
  const int row = blockIdx.x, t = threadIdx.x, w = t >> 6, l = t & 63;
  const float4* p = (const float4*)(L + (size_t)row * N_ROWS);
  __shared__ float red[8];
  float4 v[8];
#pragma unroll
  for (int i = 0; i < 8; ++i) v[i] = p[t + i * 256];
  float mx = -3.4e38f;
#pragma unroll
  for (int i = 0; i < 8; ++i)
    mx = fmaxf(mx, fmaxf(fmaxf(v[i].x, v[i].y), fmaxf(v[i].z, v[i].w)));
#pragma unroll
  for (int off = 32; off; off >>= 1) mx = fmaxf(mx, __shfl_xor(mx, off));
  if (l == 0) red[w] = mx;
  __syncthreads();
  mx = fmaxf(fmaxf(red[0], red[1]), fmaxf(red[2], red[3]));
  float e[8][4];
  float s = 0.f;
#pragma unroll
  for (int i = 0; i < 8; ++i) {
    e[i][0] = exp2f((v[i].x - mx) * LOG2E);
    e[i][1] = exp2f((v[i].y - mx) * LOG2E);
    e[i][2] = exp2f((v[i].z - mx) * LOG2E);
    e[i][3] = exp2f((v[i].w - mx) * LOG2E);
    s += (e[i][0] + e[i][1]) + (e[i][2] + e[i][3]);
  }
#pragma unroll
  for (int off = 32; off; off >>= 1) s += __shfl_xor(s, off);
  if (l == 0) red[4 + w] = s;
  __syncthreads();  // also guarantees ALL loads above finished before any write below
  float sinv = 1.0f / (red[4] + red[5] + red[6] + red[7]);
  f16* prow = P + (size_t)row * 16384;
#pragma unroll
  for (int i = 0; i < 8; ++i) {
    f16x4 h;
    h[0] = (f16)(e[i][0] * sinv);
    h[1] = (f16)(e[i][1] * sinv);
    h[2] = (f16)(e[i][2] * sinv);
    h[3] = (f16)(e[i][3] * sinv);
    *(f16x4*)(prow + (size_t)(t + i * 256) * 4) = h;
  }
}

// out[M][1024] = P[M][8192] @ (Xt[1024][8192])^T, plain f16 MFMA.
// Tile 64(M)x128(N), BK=64, 256 threads (4 waves 2x2, wave tile 32x64).
// LDS dbuf 2 x 24 KB = 48 KB -> 2 blocks/CU at grid 512; issue-early, 1 barrier/step.
__global__ __launch_bounds__(256) void gemm_pv(
    const f16* __restrict__ P,   // row stride 16384 f16 (32 KB)
    const f16* __restrict__ Xt,  // row stride 8192 f16 (16 KB)
    float* __restrict__ out) {
  __shared__ __align__(16) f16 lds[2][12288];  // per buf: A[64][64] (8KB) | B[128][64] (16KB)
  const int t = threadIdx.x, w = t >> 6, l = t & 63;
  const int bn = blockIdx.x, bm = blockIdx.y;
  const int wr = (w >> 1) * 32, wc = (w & 1) * 64;
  const char* Abase = (const char*)(P + (size_t)bm * 64 * 16384);
  const char* Bbase = (const char*)(Xt + (size_t)bn * 128 * 8192);

#define STAGE_PV(buf, ks)                                                    \
  {                                                                          \
    _Pragma("unroll") for (int i = 0; i < 2; ++i) {                          \
      int phys = i * 4096 + t * 16;                                          \
      int r = phys >> 7, q = phys & 127;                                     \
      int sq = q ^ ((r & 7) << 4);                                           \
      gload_lds16(Abase + (size_t)r * 32768 + (ks)*128 + sq,                 \
                  (char*)&lds[buf][0] + phys);                               \
    }                                                                        \
    _Pragma("unroll") for (int i = 0; i < 4; ++i) {                          \
      int phys = i * 4096 + t * 16;                                          \
      int r = phys >> 7, q = phys & 127;                                     \
      int sq = q ^ ((r & 7) << 4);                                           \
      gload_lds16(Bbase + (size_t)r * 16384 + (ks)*128 + sq,                 \
                  (char*)&lds[buf][4096] + phys);                            \
    }                                                                        \
  }

  f32x4 acc[2][4] = {};
  STAGE_PV(0, 0);
  __syncthreads();
  int cur = 0;
  for (int ks = 0; ks < 128; ++ks) {   // 128 steps x 64 f16 = K 8192
    if (ks < 127) STAGE_PV(cur ^ 1, ks + 1);
    const f16* Lb = &lds[cur][0];
#pragma unroll
    for (int ks2 = 0; ks2 < 2; ++ks2) {
      f16x8 a[2], b[4];
#pragma unroll
      for (int m = 0; m < 2; ++m) a[m] = read_frag64(Lb, wr + m * 16 + (l & 15), l, ks2);
#pragma unroll
      for (int n = 0; n < 4; ++n) b[n] = read_frag64(Lb + 4096, wc + n * 16 + (l & 15), l, ks2);
#pragma unroll
      for (int m = 0; m < 2; ++m)
#pragma unroll
        for (int n = 0; n < 4; ++n)
          acc[m][n] = __builtin_amdgcn_mfma_f32_16x16x32_f16(a[m], b[n], acc[m][n], 0, 0, 0);
    }
    __syncthreads();
    cur ^= 1;
  }
#undef STAGE_PV
#pragma unroll
  for (int m = 0; m < 2; ++m)
#pragma unroll
    for (int n = 0; n < 4; ++n)
#pragma unroll
      for (int j = 0; j < 4; ++j) {
        int row = bm * 64 + wr + m * 16 + ((l >> 4) << 2) + j;
        int col = bn * 128 + wc + n * 16 + (l & 15);
        out[(size_t)row * D_DIM + col] = acc[m][n][j];
      }
}

extern "C" void kernel_launch(void* const* d_in, const int* in_sizes, int n_in,
                              void* d_out, int out_size, void* d_ws, size_t ws_size,
                              hipStream_t stream) {
  const float* X = (const float*)d_in[0];
  const float* R = (const float*)d_in[1];
  const float* E = (const float*)d_in[2];
  float* out = (float*)d_out;

  char* p = (char*)d_ws;
  auto alloc = [&](size_t bytes) -> char* {
    char* r = p;
    p += (bytes + 255) & ~(size_t)255;
    return r;
  };
  f16* Xhi = (f16*)alloc((size_t)N_ROWS * D_DIM * 2);
  f16* Xlo = (f16*)alloc((size_t)N_ROWS * D_DIM * 2);
  f16* Yhi = (f16*)alloc((size_t)N_ROWS * D_DIM * 2);
  f16* Ylo = (f16*)alloc((size_t)N_ROWS * D_DIM * 2);
  f16* Xt  = (f16*)alloc((size_t)N_ROWS * D_DIM * 2);
  float* Lbuf = (float*)p;
  size_t front = (size_t)(p - (char*)d_ws);

  char* tail = (char*)d_ws + ws_size;
  auto alloct = [&](size_t bytes) -> char* {
    tail = (char*)(((uintptr_t)tail - bytes) & ~(uintptr_t)255);
    return tail;
  };
  f16* Rhi  = (f16*)alloct((size_t)D_DIM * D_DIM * 2);
  f16* Rlo  = (f16*)alloct((size_t)D_DIM * D_DIM * 2);
  f16* Ehi  = (f16*)alloct((size_t)D_DIM * D_DIM * 2);
  f16* Elo  = (f16*)alloct((size_t)D_DIM * D_DIM * 2);
  f16* Mthi = (f16*)alloct((size_t)D_DIM * D_DIM * 2);
  f16* Mtlo = (f16*)alloct((size_t)D_DIM * D_DIM * 2);

  size_t avail = ws_size > front ? ws_size - front : 0;
  int CH = (int)(avail / ((size_t)N_ROWS * 4));
  if (CH > N_ROWS) CH = N_ROWS;
  CH &= ~255;                       // big L-GEMM tiles 256 rows
  if (CH < 256) CH = 256;

  // 1. splits + transpose
  splitk<<<dim3((N_ROWS * D_DIM / 4 + 255) / 256), 256, 0, stream>>>(X, Xhi, Xlo, N_ROWS * D_DIM / 4);
  splitk<<<dim3((D_DIM * D_DIM / 4 + 255) / 256), 256, 0, stream>>>(R, Rhi, Rlo, D_DIM * D_DIM / 4);
  splitk<<<dim3((D_DIM * D_DIM / 4 + 255) / 256), 256, 0, stream>>>(E, Ehi, Elo, D_DIM * D_DIM / 4);
  transpose_cast<<<dim3(D_DIM / 32, N_ROWS / 32), 256, 0, stream>>>(X, Xt);

  // 2. Mt = E R^T  (so Mt^T = R E^T = M)
  gemm_abt_s<<<dim3(8, 8), 256, 0, stream>>>(Ehi, Elo, Rhi, Rlo, D_DIM, Mthi, Mtlo);
  // 3. Y = X Mt^T = X M  (512-block grid: 2 blocks/CU)
  gemm_abt_s<<<dim3(8, 64), 256, 0, stream>>>(Xhi, Xlo, Mthi, Mtlo, D_DIM, Yhi, Ylo);

  // 4. chunked: L = Y X^T / 32 ; pexp (in-place P) ; out = P @ Xt^T
  for (int c0 = 0; c0 < N_ROWS; c0 += CH) {
    int rows = (N_ROWS - c0 < CH) ? (N_ROWS - c0) : CH;
    gemm_abt_big<<<dim3(N_ROWS / 256, rows / 256), 512, 0, stream>>>(
        Yhi + (size_t)c0 * D_DIM, Ylo + (size_t)c0 * D_DIM, Xhi, Xlo,
        0.03125f, Lbuf);
    pexp<<<dim3(rows), 256, 0, stream>>>(Lbuf, (f16*)Lbuf);
    gemm_pv<<<dim3(D_DIM / 128, rows / 64), 256, 0, stream>>>(
        (const f16*)Lbuf, Xt, out + (size_t)c0 * D_DIM);
  }
}

// Round 11
// 759.512 us; speedup vs baseline: 1.1039x; 1.1039x over previous
//
#include <hip/hip_runtime.h>

// ClassicalSelfAttention: out = softmax((X R)(X E)^T / 32) @ X,  X[8192][1024] fp32.
//  - logits = X (R E^T) X^T / 32. Precompute Mt = E R^T, Y = X Mt^T, L = Y X^T / 32.
//  - Precision-critical GEMMs via f16 hi/lo split (3 MFMA products) -> ~fp32 accuracy.
//  - pexp: per-row softmax of L -> f16 P written IN-PLACE over L (row stride 16384 f16).
//  - gemm_pv: plain f16 GEMM out = P @ Xt^T, 64x128 tile, BK=64, dbuf, 2 blocks/CU.
// R2: conflict-free swizzle ((row>>1)&3)<<4. XCD chunking regressed (identity optimal).
// R3: 128^2 1-phase caps at 43%. R4: 256^2 8-wave dbuf, 1 barrier/K-step -> 58.6%/873 TF.
// R5 LESSON: min-waves beyond register budget -> full acc spill (22x).
// R6+R9 LESSON: 8-phase schedule (lopsided AND balanced variants) REGRESSES this
//   split-3 kernel at 1 blk/CU (52%/45% vs 58.6%). Line abandoned; R4 dbuf is the
//   structure. R7 BUG: retiling halved pv K-trip count (caught by absmax == max|ref|).
// R8 LESSON: grid >= 2x CUs beats per-block efficiency for the small GEMMs.
// R10: best-of recombination: R4 L-GEMM verbatim + R9 Y (gemm_abt_s, 512 blocks) +
//   R9 pv (64x128, 48KB dbuf, 2 blk/CU).

typedef _Float16 f16;
typedef _Float16 f16x4 __attribute__((ext_vector_type(4)));
typedef _Float16 f16x8 __attribute__((ext_vector_type(8)));
typedef float    f32x4 __attribute__((ext_vector_type(4)));
typedef unsigned int u32;

#define N_ROWS 8192
#define D_DIM  1024
#define LOG2E  1.44269504088896340736f

__device__ __forceinline__ void gload_lds16(const void* g, void* l) {
  __builtin_amdgcn_global_load_lds(
      (const __attribute__((address_space(1))) u32*)g,
      (__attribute__((address_space(3))) u32*)l, 16, 0, 0);
}

// ---- BK=32 tiles (64 B rows), swizzle byte^=(((row>>1)&3)<<4) ----
__device__ __forceinline__ f16x8 read_frag(const f16* tile, int row, int lane) {
  int kb = ((lane >> 4) & 3) << 4;
  int phys = row * 64 + (kb ^ (((row >> 1) & 3) << 4));
  return *(const f16x8*)((const char*)tile + phys);
}

// ---- BK=64 tiles (128 B rows), swizzle byte^=((row&7)<<4) ----
__device__ __forceinline__ f16x8 read_frag64(const f16* tile, int row, int lane, int ks2) {
  int kb = ks2 * 64 + (((lane >> 4) & 3) << 4);
  int phys = row * 128 + (kb ^ ((row & 7) << 4));
  return *(const f16x8*)((const char*)tile + phys);
}

// fp32 -> f16 hi/lo split, vectorized x4
__global__ __launch_bounds__(256) void splitk(const float* __restrict__ in,
                                              f16* __restrict__ hi, f16* __restrict__ lo,
                                              int n4) {
  int i = blockIdx.x * 256 + threadIdx.x;
  if (i >= n4) return;
  float4 v = ((const float4*)in)[i];
  float vv[4] = {v.x, v.y, v.z, v.w};
  f16x4 h, l;
#pragma unroll
  for (int j = 0; j < 4; ++j) {
    f16 hh = (f16)vv[j];
    h[j] = hh;
    l[j] = (f16)(vv[j] - (float)hh);
  }
  *(f16x4*)(hi + (size_t)i * 4) = h;
  *(f16x4*)(lo + (size_t)i * 4) = l;
}

// X[8192][1024] fp32 -> Xt[1024][8192] f16
__global__ __launch_bounds__(256) void transpose_cast(const float* __restrict__ X,
                                                      f16* __restrict__ Xt) {
  __shared__ float tile[32][33];
  int bx = blockIdx.x, by = blockIdx.y;
  int tx = threadIdx.x & 31, ty0 = threadIdx.x >> 5;
#pragma unroll
  for (int r = 0; r < 4; ++r) {
    int ty = ty0 + r * 8;
    tile[ty][tx] = X[(size_t)(by * 32 + ty) * D_DIM + bx * 32 + tx];
  }
  __syncthreads();
#pragma unroll
  for (int r = 0; r < 4; ++r) {
    int ty = ty0 + r * 8;
    Xt[(size_t)(bx * 32 + ty) * N_ROWS + by * 32 + tx] = (f16)tile[tx][ty];
  }
}

// Small split-3 GEMM for Mt (64 blocks) and Y (512 blocks). Tile 128x128, BK=32.
__global__ __launch_bounds__(256) void gemm_abt_s(
    const f16* __restrict__ Ahi, const f16* __restrict__ Alo,
    const f16* __restrict__ Bhi, const f16* __restrict__ Blo,
    int Ncols, f16* __restrict__ Chi, f16* __restrict__ Clo) {
  __shared__ __align__(16) f16 lds[4 * 4096];  // Ahi | Alo | Bhi | Blo, each [128][32]
  const int t = threadIdx.x, w = t >> 6, l = t & 63;
  const int bn = blockIdx.x, bm = blockIdx.y;
  const int wr = (w >> 1) * 64, wc = (w & 1) * 64;
  const char* srcs[4];
  srcs[0] = (const char*)(Ahi + (size_t)bm * 128 * 1024);
  srcs[1] = (const char*)(Alo + (size_t)bm * 128 * 1024);
  srcs[2] = (const char*)(Bhi + (size_t)bn * 128 * 1024);
  srcs[3] = (const char*)(Blo + (size_t)bn * 128 * 1024);
  f32x4 acc[4][4] = {};
  for (int ks = 0; ks < 32; ++ks) {
#pragma unroll
    for (int tt = 0; tt < 4; ++tt)
#pragma unroll
      for (int j = 0; j < 2; ++j) {
        int seg = j * 4 + w;
        int p = seg * 1024 + l * 16;
        int r = p >> 6;
        int sw = (p & 63) ^ (((r >> 1) & 3) << 4);
        gload_lds16(srcs[tt] + (size_t)r * 2048 + ks * 64 + sw,
                    (char*)lds + tt * 8192 + seg * 1024);
      }
    __syncthreads();
    f16x8 ah[4], al[4], bh[4], bl[4];
#pragma unroll
    for (int m = 0; m < 4; ++m) {
      int row = wr + m * 16 + (l & 15);
      ah[m] = read_frag(lds, row, l);
      al[m] = read_frag(lds + 4096, row, l);
    }
#pragma unroll
    for (int n = 0; n < 4; ++n) {
      int row = wc + n * 16 + (l & 15);
      bh[n] = read_frag(lds + 8192, row, l);
      bl[n] = read_frag(lds + 12288, row, l);
    }
#pragma unroll
    for (int m = 0; m < 4; ++m)
#pragma unroll
      for (int n = 0; n < 4; ++n) {
        acc[m][n] = __builtin_amdgcn_mfma_f32_16x16x32_f16(ah[m], bh[n], acc[m][n], 0, 0, 0);
        acc[m][n] = __builtin_amdgcn_mfma_f32_16x16x32_f16(ah[m], bl[n], acc[m][n], 0, 0, 0);
        acc[m][n] = __builtin_amdgcn_mfma_f32_16x16x32_f16(al[m], bh[n], acc[m][n], 0, 0, 0);
      }
    __syncthreads();
  }
#pragma unroll
  for (int m = 0; m < 4; ++m)
#pragma unroll
    for (int n = 0; n < 4; ++n)
#pragma unroll
      for (int j = 0; j < 4; ++j) {
        int row = bm * 128 + wr + m * 16 + ((l >> 4) << 2) + j;
        int col = bn * 128 + wc + n * 16 + (l & 15);
        float v = acc[m][n][j];
        size_t idx = (size_t)row * Ncols + col;
        f16 hh = (f16)v;
        Chi[idx] = hh;
        Clo[idx] = (f16)(v - (float)hh);
      }
}

// Big split-3 GEMM for L = Y X^T / 32 (R4 structure, verbatim).
// Tile 256x256, BK=32, 512 threads (8 waves 2Mx4N; wave tile 128x64).
// LDS dbuf 2x64 KB, issue-early staging, ONE __syncthreads per K-step.
__global__ __launch_bounds__(512, 2) void gemm_abt_big(
    const f16* __restrict__ Ahi, const f16* __restrict__ Alo,
    const f16* __restrict__ Bhi, const f16* __restrict__ Blo,
    float scale, float* __restrict__ C) {
  __shared__ __align__(16) f16 lds[2][4 * 8192];  // 2 x 64 KB
  const int t = threadIdx.x, w = t >> 6, l = t & 63;
  const int bn = blockIdx.x, bm = blockIdx.y;
  const int wm = w >> 2, wn = w & 3;
  const char* srcs[4];
  srcs[0] = (const char*)(Ahi + (size_t)bm * 256 * 1024);
  srcs[1] = (const char*)(Alo + (size_t)bm * 256 * 1024);
  srcs[2] = (const char*)(Bhi + (size_t)bn * 256 * 1024);
  srcs[3] = (const char*)(Blo + (size_t)bn * 256 * 1024);

#define STAGE_BIG(buf, kt)                                                   \
  {                                                                          \
    _Pragma("unroll") for (int rnd = 0; rnd < 8; ++rnd) {                    \
      int phys = rnd * 8192 + t * 16; /* byte within 64KB buffer */          \
      int tile = phys >> 14;                                                 \
      int r = (phys & 16383) >> 6;                                           \
      int q = phys & 63;                                                     \
      int sw = q ^ (((r >> 1) & 3) << 4);                                    \
      gload_lds16(srcs[tile] + (size_t)r * 2048 + (kt)*64 + sw,              \
                  (char*)&lds[buf][0] + phys);                               \
    }                                                                        \
  }

  f32x4 acc[8][4] = {};
  STAGE_BIG(0, 0);
  __syncthreads();
  int cur = 0;
  for (int kt = 0; kt < 32; ++kt) {
    if (kt < 31) STAGE_BIG(cur ^ 1, kt + 1);  // in flight across the compute
    const f16* Lb = &lds[cur][0];
    f16x8 bh[4], bl[4];
#pragma unroll
    for (int n = 0; n < 4; ++n) {
      int row = wn * 64 + n * 16 + (l & 15);
      bh[n] = read_frag(Lb + 16384, row, l);
      bl[n] = read_frag(Lb + 24576, row, l);
    }
#pragma unroll
    for (int m = 0; m < 8; ++m) {
      int row = wm * 128 + m * 16 + (l & 15);
      f16x8 ah = read_frag(Lb, row, l);
      f16x8 al = read_frag(Lb + 8192, row, l);
#pragma unroll
      for (int n = 0; n < 4; ++n) {
        acc[m][n] = __builtin_amdgcn_mfma_f32_16x16x32_f16(ah, bh[n], acc[m][n], 0, 0, 0);
        acc[m][n] = __builtin_amdgcn_mfma_f32_16x16x32_f16(ah, bl[n], acc[m][n], 0, 0, 0);
        acc[m][n] = __builtin_amdgcn_mfma_f32_16x16x32_f16(al, bh[n], acc[m][n], 0, 0, 0);
      }
    }
    __syncthreads();  // drains own vmcnt+lgkmcnt: buf[cur^1] staged, buf[cur] free
    cur ^= 1;
  }
#undef STAGE_BIG
#pragma unroll
  for (int m = 0; m < 8; ++m)
#pragma unroll
    for (int n = 0; n < 4; ++n)
#pragma unroll
      for (int j = 0; j < 4; ++j) {
        int row = bm * 256 + wm * 128 + m * 16 + ((l >> 4) << 2) + j;
        int col = bn * 256 + wn * 64 + n * 16 + (l & 15);
        C[(size_t)row * N_ROWS + col] = acc[m][n][j] * scale;
      }
}

// Row softmax: read L row (8192 f32) into registers, reduce max & sum(exp),
// write P = exp(L-m)/S as f16 IN-PLACE over the first half of the row.
// P row stride = 16384 f16 elements (= 32 KB = one L row).
__global__ __launch_bounds__(256) void pexp(const float* __restrict__ L,
                                            f16* __restrict__ P) {
  const int row = blockIdx.x, t = threadIdx.x, w = t >> 6, l = t & 63;
  const float4* p = (const float4*)(L + (size_t)row * N_ROWS);
  __shared__ float red[8];
  float4 v[8];
#pragma unroll
  for (int i = 0; i < 8; ++i) v[i] = p[t + i * 256];
  float mx = -3.4e38f;
#pragma unroll
  for (int i = 0; i < 8; ++i)
    mx = fmaxf(mx, fmaxf(fmaxf(v[i].x, v[i].y), fmaxf(v[i].z, v[i].w)));
#pragma unroll
  for (int off = 32; off; off >>= 1) mx = fmaxf(mx, __shfl_xor(mx, off));
  if (l == 0) red[w] = mx;
  __syncthreads();
  mx = fmaxf(fmaxf(red[0], red[1]), fmaxf(red[2], red[3]));
  float e[8][4];
  float s = 0.f;
#pragma unroll
  for (int i = 0; i < 8; ++i) {
    e[i][0] = exp2f((v[i].x - mx) * LOG2E);
    e[i][1] = exp2f((v[i].y - mx) * LOG2E);
    e[i][2] = exp2f((v[i].z - mx) * LOG2E);
    e[i][3] = exp2f((v[i].w - mx) * LOG2E);
    s += (e[i][0] + e[i][1]) + (e[i][2] + e[i][3]);
  }
#pragma unroll
  for (int off = 32; off; off >>= 1) s += __shfl_xor(s, off);
  if (l == 0) red[4 + w] = s;
  __syncthreads();  // also guarantees ALL loads above finished before any write below
  float sinv = 1.0f / (red[4] + red[5] + red[6] + red[7]);
  f16* prow = P + (size_t)row * 16384;
#pragma unroll
  for (int i = 0; i < 8; ++i) {
    f16x4 h;
    h[0] = (f16)(e[i][0] * sinv);
    h[1] = (f16)(e[i][1] * sinv);
    h[2] = (f16)(e[i][2] * sinv);
    h[3] = (f16)(e[i][3] * sinv);
    *(f16x4*)(prow + (size_t)(t + i * 256) * 4) = h;
  }
}

// out[M][1024] = P[M][8192] @ (Xt[1024][8192])^T, plain f16 MFMA.
// Tile 64(M)x128(N), BK=64, 256 threads (4 waves 2x2, wave tile 32x64).
// LDS dbuf 2 x 24 KB = 48 KB -> 2 blocks/CU at grid 512; issue-early, 1 barrier/step.
__global__ __launch_bounds__(256) void gemm_pv(
    const f16* __restrict__ P,   // row stride 16384 f16 (32 KB)
    const f16* __restrict__ Xt,  // row stride 8192 f16 (16 KB)
    float* __restrict__ out) {
  __shared__ __align__(16) f16 lds[2][12288];  // per buf: A[64][64] (8KB) | B[128][64] (16KB)
  const int t = threadIdx.x, w = t >> 6, l = t & 63;
  const int bn = blockIdx.x, bm = blockIdx.y;
  const int wr = (w >> 1) * 32, wc = (w & 1) * 64;
  const char* Abase = (const char*)(P + (size_t)bm * 64 * 16384);
  const char* Bbase = (const char*)(Xt + (size_t)bn * 128 * 8192);

#define STAGE_PV(buf, ks)                                                    \
  {                                                                          \
    _Pragma("unroll") for (int i = 0; i < 2; ++i) {                          \
      int phys = i * 4096 + t * 16;                                          \
      int r = phys >> 7, q = phys & 127;                                     \
      int sq = q ^ ((r & 7) << 4);                                           \
      gload_lds16(Abase + (size_t)r * 32768 + (ks)*128 + sq,                 \
                  (char*)&lds[buf][0] + phys);                               \
    }                                                                        \
    _Pragma("unroll") for (int i = 0; i < 4; ++i) {                          \
      int phys = i * 4096 + t * 16;                                          \
      int r = phys >> 7, q = phys & 127;                                     \
      int sq = q ^ ((r & 7) << 4);                                           \
      gload_lds16(Bbase + (size_t)r * 16384 + (ks)*128 + sq,                 \
                  (char*)&lds[buf][4096] + phys);                            \
    }                                                                        \
  }

  f32x4 acc[2][4] = {};
  STAGE_PV(0, 0);
  __syncthreads();
  int cur = 0;
  for (int ks = 0; ks < 128; ++ks) {   // 128 steps x 64 f16 = K 8192
    if (ks < 127) STAGE_PV(cur ^ 1, ks + 1);
    const f16* Lb = &lds[cur][0];
#pragma unroll
    for (int ks2 = 0; ks2 < 2; ++ks2) {
      f16x8 a[2], b[4];
#pragma unroll
      for (int m = 0; m < 2; ++m) a[m] = read_frag64(Lb, wr + m * 16 + (l & 15), l, ks2);
#pragma unroll
      for (int n = 0; n < 4; ++n) b[n] = read_frag64(Lb + 4096, wc + n * 16 + (l & 15), l, ks2);
#pragma unroll
      for (int m = 0; m < 2; ++m)
#pragma unroll
        for (int n = 0; n < 4; ++n)
          acc[m][n] = __builtin_amdgcn_mfma_f32_16x16x32_f16(a[m], b[n], acc[m][n], 0, 0, 0);
    }
    __syncthreads();
    cur ^= 1;
  }
#undef STAGE_PV
#pragma unroll
  for (int m = 0; m < 2; ++m)
#pragma unroll
    for (int n = 0; n < 4; ++n)
#pragma unroll
      for (int j = 0; j < 4; ++j) {
        int row = bm * 64 + wr + m * 16 + ((l >> 4) << 2) + j;
        int col = bn * 128 + wc + n * 16 + (l & 15);
        out[(size_t)row * D_DIM + col] = acc[m][n][j];
      }
}

extern "C" void kernel_launch(void* const* d_in, const int* in_sizes, int n_in,
                              void* d_out, int out_size, void* d_ws, size_t ws_size,
                              hipStream_t stream) {
  const float* X = (const float*)d_in[0];
  const float* R = (const float*)d_in[1];
  const float* E = (const float*)d_in[2];
  float* out = (float*)d_out;

  char* p = (char*)d_ws;
  auto alloc = [&](size_t bytes) -> char* {
    char* r = p;
    p += (bytes + 255) & ~(size_t)255;
    return r;
  };
  f16* Xhi = (f16*)alloc((size_t)N_ROWS * D_DIM * 2);
  f16* Xlo = (f16*)alloc((size_t)N_ROWS * D_DIM * 2);
  f16* Yhi = (f16*)alloc((size_t)N_ROWS * D_DIM * 2);
  f16* Ylo = (f16*)alloc((size_t)N_ROWS * D_DIM * 2);
  f16* Xt  = (f16*)alloc((size_t)N_ROWS * D_DIM * 2);
  float* Lbuf = (float*)p;
  size_t front = (size_t)(p - (char*)d_ws);

  char* tail = (char*)d_ws + ws_size;
  auto alloct = [&](size_t bytes) -> char* {
    tail = (char*)(((uintptr_t)tail - bytes) & ~(uintptr_t)255);
    return tail;
  };
  f16* Rhi  = (f16*)alloct((size_t)D_DIM * D_DIM * 2);
  f16* Rlo  = (f16*)alloct((size_t)D_DIM * D_DIM * 2);
  f16* Ehi  = (f16*)alloct((size_t)D_DIM * D_DIM * 2);
  f16* Elo  = (f16*)alloct((size_t)D_DIM * D_DIM * 2);
  f16* Mthi = (f16*)alloct((size_t)D_DIM * D_DIM * 2);
  f16* Mtlo = (f16*)alloct((size_t)D_DIM * D_DIM * 2);

  size_t avail = ws_size > front ? ws_size - front : 0;
  int CH = (int)(avail / ((size_t)N_ROWS * 4));
  if (CH > N_ROWS) CH = N_ROWS;
  CH &= ~255;                       // big L-GEMM tiles 256 rows
  if (CH < 256) CH = 256;

  // 1. splits + transpose
  splitk<<<dim3((N_ROWS * D_DIM / 4 + 255) / 256), 256, 0, stream>>>(X, Xhi, Xlo, N_ROWS * D_DIM / 4);
  splitk<<<dim3((D_DIM * D_DIM / 4 + 255) / 256), 256, 0, stream>>>(R, Rhi, Rlo, D_DIM * D_DIM / 4);
  splitk<<<dim3((D_DIM * D_DIM / 4 + 255) / 256), 256, 0, stream>>>(E, Ehi, Elo, D_DIM * D_DIM / 4);
  transpose_cast<<<dim3(D_DIM / 32, N_ROWS / 32), 256, 0, stream>>>(X, Xt);

  // 2. Mt = E R^T  (so Mt^T = R E^T = M)
  gemm_abt_s<<<dim3(8, 8), 256, 0, stream>>>(Ehi, Elo, Rhi, Rlo, D_DIM, Mthi, Mtlo);
  // 3. Y = X Mt^T = X M  (512-block grid: 2 blocks/CU)
  gemm_abt_s<<<dim3(8, 64), 256, 0, stream>>>(Xhi, Xlo, Mthi, Mtlo, D_DIM, Yhi, Ylo);

  // 4. chunked: L = Y X^T / 32 ; pexp (in-place P) ; out = P @ Xt^T
  for (int c0 = 0; c0 < N_ROWS; c0 += CH) {
    int rows = (N_ROWS - c0 < CH) ? (N_ROWS - c0) : CH;
    gemm_abt_big<<<dim3(N_ROWS / 256, rows / 256), 512, 0, stream>>>(
        Yhi + (size_t)c0 * D_DIM, Ylo + (size_t)c0 * D_DIM, Xhi, Xlo,
        0.03125f, Lbuf);
    pexp<<<dim3(rows), 256, 0, stream>>>(Lbuf, (f16*)Lbuf);
    gemm_pv<<<dim3(D_DIM / 128, rows / 64), 256, 0, stream>>>(
        (const f16*)Lbuf, Xt, out + (size_t)c0 * D_DIM);
  }
}